// Round 4
// baseline (728.044 us; speedup 1.0000x reference)
//
#include <hip/hip_runtime.h>
#include <hip/hip_fp16.h>
#include <math.h>

#define HID 64
#define IN_DIM 128
#define POS_DIM 64
#define FT_IN 192
#define BN_EPS 1e-5f
#define PAD 68   // LDS row stride (floats): 272B, 16B-aligned, conflict-light

static inline size_t align256(size_t x){ return (x + 255) & ~(size_t)255; }

// ---------------- CSR build ----------------

__global__ void k_init(float* deg, int* cnt, float* statsAll, int n){
  int i = blockIdx.x*blockDim.x + threadIdx.x;
  if (i < n){ deg[i] = 0.f; cnt[i] = 0; }
  if (i < 512) statsAll[i] = 0.f;
}

__global__ void k_degcnt(const int* __restrict__ col, const float* __restrict__ ew,
                         float* deg, int* cnt, int E){
  int e = blockIdx.x*blockDim.x + threadIdx.x;
  if (e < E){
    int c = col[e];
    atomicAdd(&deg[c], ew[e]);
    atomicAdd(&cnt[c], 1);
  }
}

__global__ void k_scanA(const int* __restrict__ cnt, int* ptr, int* bsum, int n){
  __shared__ int buf[256];
  int i = blockIdx.x*256 + threadIdx.x;
  int v = (i < n) ? cnt[i] : 0;
  buf[threadIdx.x] = v;
  __syncthreads();
  for (int off = 1; off < 256; off <<= 1){
    int t = (threadIdx.x >= off) ? buf[threadIdx.x - off] : 0;
    __syncthreads();
    buf[threadIdx.x] += t;
    __syncthreads();
  }
  if (i < n) ptr[i] = buf[threadIdx.x] - v;
  if (threadIdx.x == 255) bsum[blockIdx.x] = buf[255];
}

__global__ void k_scanB(int* bsum, int* ptr, int nblk, int n){
  __shared__ int buf[256];
  int v = (threadIdx.x < nblk) ? bsum[threadIdx.x] : 0;
  buf[threadIdx.x] = v;
  __syncthreads();
  for (int off = 1; off < 256; off <<= 1){
    int t = (threadIdx.x >= off) ? buf[threadIdx.x - off] : 0;
    __syncthreads();
    buf[threadIdx.x] += t;
    __syncthreads();
  }
  if (threadIdx.x < nblk) bsum[threadIdx.x] = buf[threadIdx.x] - v;
  if (threadIdx.x == 255) ptr[n] = buf[255];
}

// fused: finalize scan + dinv = rsqrt(deg+1)
__global__ void k_scanC(int* ptr, const int* __restrict__ bsum, int* fill,
                        const float* __restrict__ deg, float* dinv, int n){
  int i = blockIdx.x*blockDim.x + threadIdx.x;
  if (i < n){
    int p = ptr[i] + bsum[i >> 8];
    ptr[i] = p;
    fill[i] = p;
    dinv[i] = rsqrtf(deg[i] + 1.0f);
  }
}

__global__ void k_fill(const int* __restrict__ row, const int* __restrict__ col,
                       const float* __restrict__ ew, const float* __restrict__ dinv,
                       int* fill, int* csr_src, float* csr_norm, int E){
  int e = blockIdx.x*blockDim.x + threadIdx.x;
  if (e < E){
    int c = col[e], r = row[e];
    int p = atomicAdd(&fill[c], 1);
    csr_src[p] = r;
    csr_norm[p] = dinv[r]*ew[e]*dinv[c];
  }
}

// ---------------- register-tiled GEMM building block ----------------

#define MICRO_FMA(a, b, acc)                                   \
  acc[0].x = fmaf(a.x, b.x, acc[0].x);                         \
  acc[0].y = fmaf(a.x, b.y, acc[0].y);                         \
  acc[0].z = fmaf(a.x, b.z, acc[0].z);                         \
  acc[0].w = fmaf(a.x, b.w, acc[0].w);                         \
  acc[1].x = fmaf(a.y, b.x, acc[1].x);                         \
  acc[1].y = fmaf(a.y, b.y, acc[1].y);                         \
  acc[1].z = fmaf(a.y, b.z, acc[1].z);                         \
  acc[1].w = fmaf(a.y, b.w, acc[1].w);                         \
  acc[2].x = fmaf(a.z, b.x, acc[2].x);                         \
  acc[2].y = fmaf(a.z, b.y, acc[2].y);                         \
  acc[2].z = fmaf(a.z, b.z, acc[2].z);                         \
  acc[2].w = fmaf(a.z, b.w, acc[2].w);                         \
  acc[3].x = fmaf(a.w, b.x, acc[3].x);                         \
  acc[3].y = fmaf(a.w, b.y, acc[3].y);                         \
  acc[3].z = fmaf(a.w, b.z, acc[3].z);                         \
  acc[3].w = fmaf(a.w, b.w, acc[3].w);

// h0 = concat(x, pe) @ ftW ; bias skipped (cancels in BN); fused BN stats.
__global__ __launch_bounds__(256) void k_h0(
    const float* __restrict__ x, const int* __restrict__ positions,
    const float* __restrict__ ftW, float* __restrict__ h0, float* stats, int N)
{
  __shared__ __align__(16) float Xs[32*PAD];   // transposed [k][node]
  __shared__ __align__(16) float Wc[32*64];    // [k][col]
  __shared__ float redS[16*64];
  __shared__ float redQ[16*64];
  int tx = threadIdx.x;
  int n0 = blockIdx.x * 64;
  int c4 = (tx & 15) * 4;
  int r4 = (tx >> 4) * 4;
  float4 acc[4];
  acc[0] = acc[1] = acc[2] = acc[3] = make_float4(0.f,0.f,0.f,0.f);

  for (int kc = 0; kc < 6; ++kc){
    #pragma unroll
    for (int i = 0; i < 8; ++i)
      Wc[tx + i*256] = ftW[kc*2048 + tx + i*256];
    if (kc < 4){
      #pragma unroll
      for (int i = 0; i < 2; ++i){
        int s = tx + i*256;
        int row = s >> 3, kk = (s & 7) * 4;
        float4 v = make_float4(0.f,0.f,0.f,0.f);
        int n = n0 + row;
        if (n < N) v = *(const float4*)&x[(size_t)n*IN_DIM + kc*32 + kk];
        Xs[(kk+0)*PAD + row] = v.x;
        Xs[(kk+1)*PAD + row] = v.y;
        Xs[(kk+2)*PAD + row] = v.z;
        Xs[(kk+3)*PAD + row] = v.w;
      }
    } else {
      #pragma unroll
      for (int i = 0; i < 4; ++i){
        int s = tx + i*256;
        int m = s & 63, jj = s >> 6;
        int j = (kc-4)*16 + jj;
        int n = n0 + m;
        float sv = 0.f, cv = 0.f;
        if (n < N){
          float ang = (float)positions[n] * expf((float)(2*j) * -0.14391157f);
          sv = sinf(ang); cv = cosf(ang);
        }
        Xs[(2*jj+0)*PAD + m] = sv;
        Xs[(2*jj+1)*PAD + m] = cv;
      }
    }
    __syncthreads();
    #pragma unroll 8
    for (int k = 0; k < 32; ++k){
      float4 a = *(const float4*)(Xs + k*PAD + r4);
      float4 b = *(const float4*)(Wc + k*64 + c4);
      MICRO_FMA(a, b, acc);
    }
    __syncthreads();
  }

  float cs[4] = {0,0,0,0}, cq[4] = {0,0,0,0};
  #pragma unroll
  for (int i = 0; i < 4; ++i){
    int n = n0 + r4 + i;
    if (n < N) *(float4*)&h0[(size_t)n*HID + c4] = acc[i];
    float4 v = (n < N) ? acc[i] : make_float4(0,0,0,0);
    cs[0] += v.x; cs[1] += v.y; cs[2] += v.z; cs[3] += v.w;
    cq[0] += v.x*v.x; cq[1] += v.y*v.y; cq[2] += v.z*v.z; cq[3] += v.w*v.w;
  }
  int g = tx >> 4;
  #pragma unroll
  for (int j = 0; j < 4; ++j){
    redS[g*64 + c4 + j] = cs[j];
    redQ[g*64 + c4 + j] = cq[j];
  }
  __syncthreads();
  if (tx < 64){
    float s = 0.f, q = 0.f;
    #pragma unroll
    for (int gg = 0; gg < 16; ++gg){ s += redS[gg*64 + tx]; q += redQ[gg*64 + tx]; }
    atomicAdd(&stats[tx], s);
    atomicAdd(&stats[64+tx], q);
  }
}

// fused: coef from stats (inline BN finalize); h_new = relu(aggb*scale+shift)
// (+ hbuf if residual); hbuf = h_new; hw = h_new @ W (fp16)
__global__ __launch_bounds__(256) void k_layer(
    const float* __restrict__ aggb, const float* __restrict__ stats,
    const float* __restrict__ gamma, const float* __restrict__ beta, float invN,
    float* __restrict__ hbuf, const float* __restrict__ W,
    __half* __restrict__ hwh, int N, int residual)
{
  __shared__ __align__(16) float Ws[64*64];
  __shared__ __align__(16) float Hs[64*PAD];
  __shared__ float coefS[128];
  int tx = threadIdx.x;
  int n0 = blockIdx.x * 64;
  if (tx < 64){
    float s = stats[tx], s2 = stats[64+tx];
    float mean = s * invN;
    float var = s2 * invN - mean*mean;
    float scale = rsqrtf(var + BN_EPS) * gamma[tx];
    coefS[tx] = scale;
    coefS[64+tx] = beta[tx] - mean*scale;
  }
  #pragma unroll
  for (int i = 0; i < 16; ++i) Ws[tx + i*256] = W[tx + i*256];
  __syncthreads();
  #pragma unroll
  for (int i = 0; i < 4; ++i){
    int s = tx + i*256;
    int row = s >> 4, cc = (s & 15) * 4;
    int n = n0 + row;
    float4 r = make_float4(0.f,0.f,0.f,0.f);
    if (n < N){
      float4 v = *(const float4*)&aggb[(size_t)n*HID + cc];
      r.x = fmaxf(fmaf(v.x, coefS[cc+0], coefS[64+cc+0]), 0.f);
      r.y = fmaxf(fmaf(v.y, coefS[cc+1], coefS[64+cc+1]), 0.f);
      r.z = fmaxf(fmaf(v.z, coefS[cc+2], coefS[64+cc+2]), 0.f);
      r.w = fmaxf(fmaf(v.w, coefS[cc+3], coefS[64+cc+3]), 0.f);
      if (residual){
        float4 o = *(const float4*)&hbuf[(size_t)n*HID + cc];
        r.x += o.x; r.y += o.y; r.z += o.z; r.w += o.w;
      }
      *(float4*)&hbuf[(size_t)n*HID + cc] = r;
    }
    Hs[(cc+0)*PAD + row] = r.x;
    Hs[(cc+1)*PAD + row] = r.y;
    Hs[(cc+2)*PAD + row] = r.z;
    Hs[(cc+3)*PAD + row] = r.w;
  }
  __syncthreads();
  int c4 = (tx & 15) * 4;
  int r4 = (tx >> 4) * 4;
  float4 acc[4];
  acc[0] = acc[1] = acc[2] = acc[3] = make_float4(0.f,0.f,0.f,0.f);
  #pragma unroll 8
  for (int k = 0; k < 64; ++k){
    float4 a = *(const float4*)(Hs + k*PAD + r4);
    float4 b = *(const float4*)(Ws + k*64 + c4);
    MICRO_FMA(a, b, acc);
  }
  #pragma unroll
  for (int i = 0; i < 4; ++i){
    int n = n0 + r4 + i;
    if (n < N){
      __half2 h01 = __floats2half2_rn(acc[i].x, acc[i].y);
      __half2 h23 = __floats2half2_rn(acc[i].z, acc[i].w);
      *(__half2*)&hwh[(size_t)n*HID + c4]     = h01;
      *(__half2*)&hwh[(size_t)n*HID + c4 + 2] = h23;
    }
  }
}

// agg[n][k] = dinv[n]^2 * hw[n][k] + sum_e norm[e]*hw[src[e]][k]  (hw fp16)
// subgroup-parallel: 4 edges per wave-gather, 8B/lane; 2 chains; 2 nodes/wave
__global__ __launch_bounds__(256) void k_agg(
    const __half* __restrict__ hwh, const int* __restrict__ ptr,
    const int* __restrict__ csr_src, const float* __restrict__ csr_norm,
    const float* __restrict__ dinv, float* __restrict__ agg,
    float* stats, int N)
{
  __shared__ float redS[4*64];
  __shared__ float redQ[4*64];
  int tx = threadIdx.x;
  int lane = tx & 63, w = tx >> 6;
  int sg = lane >> 4;          // subgroup 0..3 (edge slot)
  int k4 = (lane & 15) * 4;    // feature base
  float4 csum = make_float4(0,0,0,0), csq = make_float4(0,0,0,0);
  int n0 = blockIdx.x * 8 + w*2;
  for (int it = 0; it < 2; ++it){
    int n = n0 + it;
    if (n >= N) break;                     // wave-uniform
    float di = dinv[n];
    float4 acc = make_float4(0,0,0,0);
    float4 acc2 = make_float4(0,0,0,0);
    {
      uint2 u = *(const uint2*)&hwh[(size_t)n*HID + k4];
      float2 f01 = __half22float2(*(const __half2*)&u.x);
      float2 f23 = __half22float2(*(const __half2*)&u.y);
      if (sg == 0){
        float d2 = di*di;
        acc.x = d2*f01.x; acc.y = d2*f01.y; acc.z = d2*f23.x; acc.w = d2*f23.y;
      }
    }
    int e0 = ptr[n], e1 = ptr[n+1];
    for (int eb = e0; eb < e1; eb += 64){
      int m = e1 - eb; if (m > 64) m = 64;
      int   se = (lane < m) ? csr_src[eb + lane] : 0;
      float ne = (lane < m) ? csr_norm[eb + lane] : 0.f;
      int j = 0;
      for (; j + 8 <= m; j += 8){
        int   sA = __shfl(se, j + sg,     64);
        float wA = __shfl(ne, j + sg,     64);
        int   sB = __shfl(se, j + 4 + sg, 64);
        float wB = __shfl(ne, j + 4 + sg, 64);
        uint2 uA = *(const uint2*)&hwh[(size_t)sA*HID + k4];
        uint2 uB = *(const uint2*)&hwh[(size_t)sB*HID + k4];
        float2 a01 = __half22float2(*(const __half2*)&uA.x);
        float2 a23 = __half22float2(*(const __half2*)&uA.y);
        float2 b01 = __half22float2(*(const __half2*)&uB.x);
        float2 b23 = __half22float2(*(const __half2*)&uB.y);
        acc.x  = fmaf(wA, a01.x, acc.x);
        acc.y  = fmaf(wA, a01.y, acc.y);
        acc.z  = fmaf(wA, a23.x, acc.z);
        acc.w  = fmaf(wA, a23.y, acc.w);
        acc2.x = fmaf(wB, b01.x, acc2.x);
        acc2.y = fmaf(wB, b01.y, acc2.y);
        acc2.z = fmaf(wB, b23.x, acc2.z);
        acc2.w = fmaf(wB, b23.y, acc2.w);
      }
      for (; j < m; j += 4){
        int idx = j + sg;                  // idx < 64 always
        int   sA = __shfl(se, idx, 64);    // se/ne are 0 beyond m
        float wA = __shfl(ne, idx, 64);
        uint2 uA = *(const uint2*)&hwh[(size_t)sA*HID + k4];
        float2 a01 = __half22float2(*(const __half2*)&uA.x);
        float2 a23 = __half22float2(*(const __half2*)&uA.y);
        acc.x = fmaf(wA, a01.x, acc.x);
        acc.y = fmaf(wA, a01.y, acc.y);
        acc.z = fmaf(wA, a23.x, acc.z);
        acc.w = fmaf(wA, a23.y, acc.w);
      }
    }
    acc.x += acc2.x; acc.y += acc2.y; acc.z += acc2.z; acc.w += acc2.w;
    // reduce across the 4 subgroups
    acc.x += __shfl_xor(acc.x, 16, 64);
    acc.y += __shfl_xor(acc.y, 16, 64);
    acc.z += __shfl_xor(acc.z, 16, 64);
    acc.w += __shfl_xor(acc.w, 16, 64);
    acc.x += __shfl_xor(acc.x, 32, 64);
    acc.y += __shfl_xor(acc.y, 32, 64);
    acc.z += __shfl_xor(acc.z, 32, 64);
    acc.w += __shfl_xor(acc.w, 32, 64);
    if (sg == 0){
      *(float4*)&agg[(size_t)n*HID + k4] = acc;
      csum.x += acc.x; csum.y += acc.y; csum.z += acc.z; csum.w += acc.w;
      csq.x += acc.x*acc.x; csq.y += acc.y*acc.y;
      csq.z += acc.z*acc.z; csq.w += acc.w*acc.w;
    }
  }
  if (sg == 0){
    *(float4*)&redS[w*64 + k4] = csum;
    *(float4*)&redQ[w*64 + k4] = csq;
  }
  __syncthreads();
  if (tx < 64){
    float s = redS[tx] + redS[64+tx] + redS[128+tx] + redS[192+tx];
    float q = redQ[tx] + redQ[64+tx] + redQ[128+tx] + redQ[192+tx];
    atomicAdd(&stats[tx], s);
    atomicAdd(&stats[64+tx], q);
  }
}

// fused final: coef inline; h3 = relu(aggb*scale+shift)+hbuf ;
// out = relu(h3@W1+b1)@W2+b2
__global__ __launch_bounds__(256) void k_out(
    const float* __restrict__ aggb, const float* __restrict__ stats,
    const float* __restrict__ gamma, const float* __restrict__ beta, float invN,
    const float* __restrict__ hbuf,
    const float* __restrict__ W1, const float* __restrict__ b1,
    const float* __restrict__ W2, const float* __restrict__ b2,
    float* __restrict__ out, int N)
{
  __shared__ __align__(16) float Hs[64*PAD];
  __shared__ float red[256];
  __shared__ float coefS[128];
  int tx = threadIdx.x;
  int n0 = blockIdx.x * 64;
  if (tx < 64){
    float s = stats[tx], s2 = stats[64+tx];
    float mean = s * invN;
    float var = s2 * invN - mean*mean;
    float scale = rsqrtf(var + BN_EPS) * gamma[tx];
    coefS[tx] = scale;
    coefS[64+tx] = beta[tx] - mean*scale;
  }
  __syncthreads();
  #pragma unroll
  for (int i = 0; i < 4; ++i){
    int s = tx + i*256;
    int row = s >> 4, cc = (s & 15) * 4;
    int n = n0 + row;
    float4 r = make_float4(0.f,0.f,0.f,0.f);
    if (n < N){
      float4 v = *(const float4*)&aggb[(size_t)n*HID + cc];
      r.x = fmaxf(fmaf(v.x, coefS[cc+0], coefS[64+cc+0]), 0.f);
      r.y = fmaxf(fmaf(v.y, coefS[cc+1], coefS[64+cc+1]), 0.f);
      r.z = fmaxf(fmaf(v.z, coefS[cc+2], coefS[64+cc+2]), 0.f);
      r.w = fmaxf(fmaf(v.w, coefS[cc+3], coefS[64+cc+3]), 0.f);
      float4 o = *(const float4*)&hbuf[(size_t)n*HID + cc];
      r.x += o.x; r.y += o.y; r.z += o.z; r.w += o.w;
    }
    Hs[(cc+0)*PAD + row] = r.x;
    Hs[(cc+1)*PAD + row] = r.y;
    Hs[(cc+2)*PAD + row] = r.z;
    Hs[(cc+3)*PAD + row] = r.w;
  }
  __syncthreads();
  int m = tx & 63, w = tx >> 6, j0 = w*8;
  float acc[8] = {0,0,0,0,0,0,0,0};
  #pragma unroll 8
  for (int k = 0; k < 64; ++k){
    float hv = Hs[k*PAD + m];
    #pragma unroll
    for (int j = 0; j < 8; ++j)
      acc[j] = fmaf(hv, W1[k*32 + j0 + j], acc[j]);
  }
  float part = 0.f;
  #pragma unroll
  for (int j = 0; j < 8; ++j)
    part += fmaxf(acc[j] + b1[j0+j], 0.f) * W2[j0+j];
  red[w*64 + m] = part;
  __syncthreads();
  if (tx < 64){
    int n = n0 + tx;
    if (n < N) out[n] = red[tx] + red[64+tx] + red[128+tx] + red[192+tx] + b2[0];
  }
}

extern "C" void kernel_launch(void* const* d_in, const int* in_sizes, int n_in,
                              void* d_out, int out_size, void* d_ws, size_t ws_size,
                              hipStream_t stream)
{
  const float* x         = (const float*)d_in[0];
  const int*   ei        = (const int*)d_in[1];
  const float* ew        = (const float*)d_in[2];
  const int*   positions = (const int*)d_in[3];
  const float* ftW       = (const float*)d_in[4];
  const float* ft_gamma  = (const float*)d_in[6];
  const float* ft_beta   = (const float*)d_in[7];
  const float* convW     = (const float*)d_in[8];
  const float* bn_gamma  = (const float*)d_in[10];
  const float* bn_beta   = (const float*)d_in[11];
  const float* outW1     = (const float*)d_in[12];
  const float* outb1     = (const float*)d_in[13];
  const float* outW2     = (const float*)d_in[14];
  const float* outb2     = (const float*)d_in[15];
  float* out = (float*)d_out;

  int N = in_sizes[0] / IN_DIM;
  int E = in_sizes[1] / 2;
  const int* row  = ei;
  const int* colv = ei + E;

  char* p = (char*)d_ws;
  auto alloc = [&](size_t bytes){ char* r = p; p += align256(bytes); return r; };
  float* deg      = (float*)alloc((size_t)N*4);
  float* dinv     = (float*)alloc((size_t)N*4);
  int*   cnt      = (int*)  alloc((size_t)N*4);
  int*   ptr      = (int*)  alloc((size_t)(N+1)*4);
  int*   fill     = (int*)  alloc((size_t)N*4);
  int*   bsum     = (int*)  alloc((size_t)((N+255)/256)*4);
  int*   csr_src  = (int*)  alloc((size_t)E*4);
  float* csr_norm = (float*)alloc((size_t)E*4);
  __half* hwh     = (__half*)alloc((size_t)N*HID*2);
  float* aggb     = (float*)alloc((size_t)N*HID*4);
  float* hbuf     = (float*)alloc((size_t)N*HID*4);
  float* statsAll = (float*)alloc(512*4);   // 4 x 128 (ft, layer0..2)

  float* stats0 = statsAll;
  float* stats1 = statsAll + 128;
  float* stats2 = statsAll + 256;
  float* stats3 = statsAll + 384;

  int nb_n  = (N+255)/256;
  int nb_e  = (E+255)/256;
  int nblk  = (N+255)/256;
  int nb64  = (N+63)/64;
  int nb8   = (N+7)/8;
  float invN = 1.0f/(float)N;

  // CSR build (once; shared by all 3 layers)
  k_init  <<<nb_n,256,0,stream>>>(deg,cnt,statsAll,N);
  k_degcnt<<<nb_e,256,0,stream>>>(colv,ew,deg,cnt,E);
  k_scanA <<<nblk,256,0,stream>>>(cnt,ptr,bsum,N);
  k_scanB <<<1,256,0,stream>>>(bsum,ptr,nblk,N);
  k_scanC <<<nb_n,256,0,stream>>>(ptr,bsum,fill,deg,dinv,N);
  k_fill  <<<nb_e,256,0,stream>>>(row,colv,ew,dinv,fill,csr_src,csr_norm,E);

  // feature transform (pre-BN values -> aggb, stats fused)
  k_h0  <<<nb64,256,0,stream>>>(x,positions,ftW,aggb,stats0,N);

  // GCN layers (BN coef computed inline from stats of the previous stage)
  float* statsIn[4]  = {stats0, stats1, stats2, stats3};
  for (int i = 0; i < 3; ++i){
    const float* g = (i==0) ? ft_gamma : bn_gamma + (size_t)(i-1)*HID;
    const float* b = (i==0) ? ft_beta  : bn_beta  + (size_t)(i-1)*HID;
    k_layer<<<nb64,256,0,stream>>>(aggb,statsIn[i],g,b,invN,hbuf,
                                   convW + (size_t)i*HID*HID,hwh,N,(i>0)?1:0);
    k_agg  <<<nb8,256,0,stream>>>(hwh,ptr,csr_src,csr_norm,dinv,aggb,statsIn[i+1],N);
  }

  // final apply + output MLP
  k_out<<<nb64,256,0,stream>>>(aggb,stats3,bn_gamma+2*HID,bn_beta+2*HID,invN,
                               hbuf,outW1,outb1,outW2,outb2,out,N);
}

// Round 5
// 533.488 us; speedup vs baseline: 1.3647x; 1.3647x over previous
//
#include <hip/hip_runtime.h>
#include <hip/hip_fp16.h>
#include <math.h>

#define HID 64
#define IN_DIM 128
#define POS_DIM 64
#define FT_IN 192
#define BN_EPS 1e-5f
#define PAD 68   // LDS row stride (floats): 272B, 16B-aligned, conflict-light

static inline size_t align256(size_t x){ return (x + 255) & ~(size_t)255; }

// ---------------- CSR build ----------------

__global__ void k_init(float* deg, int* cnt, float* statsAll, int n){
  int i = blockIdx.x*blockDim.x + threadIdx.x;
  if (i < n){ deg[i] = 0.f; cnt[i] = 0; }
  if (i < 512) statsAll[i] = 0.f;
}

__global__ void k_degcnt(const int* __restrict__ col, const float* __restrict__ ew,
                         float* deg, int* cnt, int E){
  int e = blockIdx.x*blockDim.x + threadIdx.x;
  if (e < E){
    int c = col[e];
    atomicAdd(&deg[c], ew[e]);
    atomicAdd(&cnt[c], 1);
  }
}

__global__ void k_scanA(const int* __restrict__ cnt, int* ptr, int* bsum, int n){
  __shared__ int buf[256];
  int i = blockIdx.x*256 + threadIdx.x;
  int v = (i < n) ? cnt[i] : 0;
  buf[threadIdx.x] = v;
  __syncthreads();
  for (int off = 1; off < 256; off <<= 1){
    int t = (threadIdx.x >= off) ? buf[threadIdx.x - off] : 0;
    __syncthreads();
    buf[threadIdx.x] += t;
    __syncthreads();
  }
  if (i < n) ptr[i] = buf[threadIdx.x] - v;
  if (threadIdx.x == 255) bsum[blockIdx.x] = buf[255];
}

__global__ void k_scanB(int* bsum, int* ptr, int nblk, int n){
  __shared__ int buf[256];
  int v = (threadIdx.x < nblk) ? bsum[threadIdx.x] : 0;
  buf[threadIdx.x] = v;
  __syncthreads();
  for (int off = 1; off < 256; off <<= 1){
    int t = (threadIdx.x >= off) ? buf[threadIdx.x - off] : 0;
    __syncthreads();
    buf[threadIdx.x] += t;
    __syncthreads();
  }
  if (threadIdx.x < nblk) bsum[threadIdx.x] = buf[threadIdx.x] - v;
  if (threadIdx.x == 255) ptr[n] = buf[255];
}

// fused: finalize scan + dinv = rsqrt(deg+1)
__global__ void k_scanC(int* ptr, const int* __restrict__ bsum, int* fill,
                        const float* __restrict__ deg, float* dinv, int n){
  int i = blockIdx.x*blockDim.x + threadIdx.x;
  if (i < n){
    int p = ptr[i] + bsum[i >> 8];
    ptr[i] = p;
    fill[i] = p;
    dinv[i] = rsqrtf(deg[i] + 1.0f);
  }
}

// edges[p] = {src, bits(norm)} interleaved for one-load edge metadata
__global__ void k_fill(const int* __restrict__ row, const int* __restrict__ col,
                       const float* __restrict__ ew, const float* __restrict__ dinv,
                       int* fill, int2* edges, int E){
  int e = blockIdx.x*blockDim.x + threadIdx.x;
  if (e < E){
    int c = col[e], r = row[e];
    int p = atomicAdd(&fill[c], 1);
    float nrm = dinv[r]*ew[e]*dinv[c];
    edges[p] = make_int2(r, __float_as_int(nrm));
  }
}

// ---------------- register-tiled GEMM building block ----------------

#define MICRO_FMA(a, b, acc)                                   \
  acc[0].x = fmaf(a.x, b.x, acc[0].x);                         \
  acc[0].y = fmaf(a.x, b.y, acc[0].y);                         \
  acc[0].z = fmaf(a.x, b.z, acc[0].z);                         \
  acc[0].w = fmaf(a.x, b.w, acc[0].w);                         \
  acc[1].x = fmaf(a.y, b.x, acc[1].x);                         \
  acc[1].y = fmaf(a.y, b.y, acc[1].y);                         \
  acc[1].z = fmaf(a.y, b.z, acc[1].z);                         \
  acc[1].w = fmaf(a.y, b.w, acc[1].w);                         \
  acc[2].x = fmaf(a.z, b.x, acc[2].x);                         \
  acc[2].y = fmaf(a.z, b.y, acc[2].y);                         \
  acc[2].z = fmaf(a.z, b.z, acc[2].z);                         \
  acc[2].w = fmaf(a.z, b.w, acc[2].w);                         \
  acc[3].x = fmaf(a.w, b.x, acc[3].x);                         \
  acc[3].y = fmaf(a.w, b.y, acc[3].y);                         \
  acc[3].z = fmaf(a.w, b.z, acc[3].z);                         \
  acc[3].w = fmaf(a.w, b.w, acc[3].w);

// h0 = concat(x, pe) @ ftW ; bias skipped (cancels in BN); fused BN stats.
__global__ __launch_bounds__(256) void k_h0(
    const float* __restrict__ x, const int* __restrict__ positions,
    const float* __restrict__ ftW, float* __restrict__ h0, float* stats, int N)
{
  __shared__ __align__(16) float Xs[32*PAD];   // transposed [k][node]
  __shared__ __align__(16) float Wc[32*64];    // [k][col]
  __shared__ float redS[16*64];
  __shared__ float redQ[16*64];
  int tx = threadIdx.x;
  int n0 = blockIdx.x * 64;
  int c4 = (tx & 15) * 4;
  int r4 = (tx >> 4) * 4;
  float4 acc[4];
  acc[0] = acc[1] = acc[2] = acc[3] = make_float4(0.f,0.f,0.f,0.f);

  for (int kc = 0; kc < 6; ++kc){
    #pragma unroll
    for (int i = 0; i < 8; ++i)
      Wc[tx + i*256] = ftW[kc*2048 + tx + i*256];
    if (kc < 4){
      #pragma unroll
      for (int i = 0; i < 2; ++i){
        int s = tx + i*256;
        int row = s >> 3, kk = (s & 7) * 4;
        float4 v = make_float4(0.f,0.f,0.f,0.f);
        int n = n0 + row;
        if (n < N) v = *(const float4*)&x[(size_t)n*IN_DIM + kc*32 + kk];
        Xs[(kk+0)*PAD + row] = v.x;
        Xs[(kk+1)*PAD + row] = v.y;
        Xs[(kk+2)*PAD + row] = v.z;
        Xs[(kk+3)*PAD + row] = v.w;
      }
    } else {
      #pragma unroll
      for (int i = 0; i < 4; ++i){
        int s = tx + i*256;
        int m = s & 63, jj = s >> 6;
        int j = (kc-4)*16 + jj;
        int n = n0 + m;
        float sv = 0.f, cv = 0.f;
        if (n < N){
          float ang = (float)positions[n] * expf((float)(2*j) * -0.14391157f);
          sv = sinf(ang); cv = cosf(ang);
        }
        Xs[(2*jj+0)*PAD + m] = sv;
        Xs[(2*jj+1)*PAD + m] = cv;
      }
    }
    __syncthreads();
    #pragma unroll 8
    for (int k = 0; k < 32; ++k){
      float4 a = *(const float4*)(Xs + k*PAD + r4);
      float4 b = *(const float4*)(Wc + k*64 + c4);
      MICRO_FMA(a, b, acc);
    }
    __syncthreads();
  }

  float cs[4] = {0,0,0,0}, cq[4] = {0,0,0,0};
  #pragma unroll
  for (int i = 0; i < 4; ++i){
    int n = n0 + r4 + i;
    if (n < N) *(float4*)&h0[(size_t)n*HID + c4] = acc[i];
    float4 v = (n < N) ? acc[i] : make_float4(0,0,0,0);
    cs[0] += v.x; cs[1] += v.y; cs[2] += v.z; cs[3] += v.w;
    cq[0] += v.x*v.x; cq[1] += v.y*v.y; cq[2] += v.z*v.z; cq[3] += v.w*v.w;
  }
  int g = tx >> 4;
  #pragma unroll
  for (int j = 0; j < 4; ++j){
    redS[g*64 + c4 + j] = cs[j];
    redQ[g*64 + c4 + j] = cq[j];
  }
  __syncthreads();
  if (tx < 64){
    float s = 0.f, q = 0.f;
    #pragma unroll
    for (int gg = 0; gg < 16; ++gg){ s += redS[gg*64 + tx]; q += redQ[gg*64 + tx]; }
    atomicAdd(&stats[tx], s);
    atomicAdd(&stats[64+tx], q);
  }
}

// fused: coef from stats (inline BN finalize); h_new = relu(aggb*scale+shift)
// (+ hbuf if residual); hbuf = h_new; hw = h_new @ W (fp16)
__global__ __launch_bounds__(256) void k_layer(
    const float* __restrict__ aggb, const float* __restrict__ stats,
    const float* __restrict__ gamma, const float* __restrict__ beta, float invN,
    float* __restrict__ hbuf, const float* __restrict__ W,
    __half* __restrict__ hwh, int N, int residual)
{
  __shared__ __align__(16) float Ws[64*64];
  __shared__ __align__(16) float Hs[64*PAD];
  __shared__ float coefS[128];
  int tx = threadIdx.x;
  int n0 = blockIdx.x * 64;
  if (tx < 64){
    float s = stats[tx], s2 = stats[64+tx];
    float mean = s * invN;
    float var = s2 * invN - mean*mean;
    float scale = rsqrtf(var + BN_EPS) * gamma[tx];
    coefS[tx] = scale;
    coefS[64+tx] = beta[tx] - mean*scale;
  }
  #pragma unroll
  for (int i = 0; i < 16; ++i) Ws[tx + i*256] = W[tx + i*256];
  __syncthreads();
  #pragma unroll
  for (int i = 0; i < 4; ++i){
    int s = tx + i*256;
    int row = s >> 4, cc = (s & 15) * 4;
    int n = n0 + row;
    float4 r = make_float4(0.f,0.f,0.f,0.f);
    if (n < N){
      float4 v = *(const float4*)&aggb[(size_t)n*HID + cc];
      r.x = fmaxf(fmaf(v.x, coefS[cc+0], coefS[64+cc+0]), 0.f);
      r.y = fmaxf(fmaf(v.y, coefS[cc+1], coefS[64+cc+1]), 0.f);
      r.z = fmaxf(fmaf(v.z, coefS[cc+2], coefS[64+cc+2]), 0.f);
      r.w = fmaxf(fmaf(v.w, coefS[cc+3], coefS[64+cc+3]), 0.f);
      if (residual){
        float4 o = *(const float4*)&hbuf[(size_t)n*HID + cc];
        r.x += o.x; r.y += o.y; r.z += o.z; r.w += o.w;
      }
      *(float4*)&hbuf[(size_t)n*HID + cc] = r;
    }
    Hs[(cc+0)*PAD + row] = r.x;
    Hs[(cc+1)*PAD + row] = r.y;
    Hs[(cc+2)*PAD + row] = r.z;
    Hs[(cc+3)*PAD + row] = r.w;
  }
  __syncthreads();
  int c4 = (tx & 15) * 4;
  int r4 = (tx >> 4) * 4;
  float4 acc[4];
  acc[0] = acc[1] = acc[2] = acc[3] = make_float4(0.f,0.f,0.f,0.f);
  #pragma unroll 8
  for (int k = 0; k < 64; ++k){
    float4 a = *(const float4*)(Hs + k*PAD + r4);
    float4 b = *(const float4*)(Ws + k*64 + c4);
    MICRO_FMA(a, b, acc);
  }
  #pragma unroll
  for (int i = 0; i < 4; ++i){
    int n = n0 + r4 + i;
    if (n < N){
      __half2 h01 = __floats2half2_rn(acc[i].x, acc[i].y);
      __half2 h23 = __floats2half2_rn(acc[i].z, acc[i].w);
      *(__half2*)&hwh[(size_t)n*HID + c4]     = h01;
      *(__half2*)&hwh[(size_t)n*HID + c4 + 2] = h23;
    }
  }
}

// agg[n][k] = dinv[n]^2 * hw[n][k] + sum_e norm[e]*hw[src[e]][k]  (hw fp16)
// lane = feature; per edge: one uniform 8B metadata load -> scalar-indexed
// 128B row gather; 8 independent chains for MLP.
__global__ __launch_bounds__(256) void k_agg(
    const __half* __restrict__ hwh, const int* __restrict__ ptr,
    const int2* __restrict__ edges, const float* __restrict__ dinv,
    float* __restrict__ agg, float* stats, int N)
{
  __shared__ float red[512];
  int tx = threadIdx.x;
  int k = tx & 63, w = tx >> 6;
  int n0 = blockIdx.x * 16;
  float ssum = 0.f, ssq = 0.f;
  #define GATH(P) __half2float(hwh[(size_t)((int)__builtin_amdgcn_readfirstlane((P).x))*HID + k])
  for (int it = 0; it < 4; ++it){
    int n = n0 + w*4 + it;
    if (n < N){
      float di = dinv[n];
      float acc0 = di*di*__half2float(hwh[(size_t)n*HID + k]);
      float acc1 = 0.f, acc2 = 0.f, acc3 = 0.f;
      float acc4 = 0.f, acc5 = 0.f, acc6 = 0.f, acc7 = 0.f;
      int e0 = ptr[n], e1 = ptr[n+1];
      int e = e0;
      for (; e + 8 <= e1; e += 8){
        int2 p0 = edges[e+0], p1 = edges[e+1], p2 = edges[e+2], p3 = edges[e+3];
        int2 p4 = edges[e+4], p5 = edges[e+5], p6 = edges[e+6], p7 = edges[e+7];
        float g0 = GATH(p0);
        float g1 = GATH(p1);
        float g2 = GATH(p2);
        float g3 = GATH(p3);
        float g4 = GATH(p4);
        float g5 = GATH(p5);
        float g6 = GATH(p6);
        float g7 = GATH(p7);
        acc0 = fmaf(__int_as_float(p0.y), g0, acc0);
        acc1 = fmaf(__int_as_float(p1.y), g1, acc1);
        acc2 = fmaf(__int_as_float(p2.y), g2, acc2);
        acc3 = fmaf(__int_as_float(p3.y), g3, acc3);
        acc4 = fmaf(__int_as_float(p4.y), g4, acc4);
        acc5 = fmaf(__int_as_float(p5.y), g5, acc5);
        acc6 = fmaf(__int_as_float(p6.y), g6, acc6);
        acc7 = fmaf(__int_as_float(p7.y), g7, acc7);
      }
      for (; e < e1; ++e){
        int2 p = edges[e];
        acc0 = fmaf(__int_as_float(p.y), GATH(p), acc0);
      }
      float acc = ((acc0 + acc1) + (acc2 + acc3)) + ((acc4 + acc5) + (acc6 + acc7));
      agg[(size_t)n*HID + k] = acc;
      ssum += acc; ssq += acc*acc;
    }
  }
  #undef GATH
  red[tx] = ssum; red[256+tx] = ssq;
  __syncthreads();
  if (tx < 64){
    float s  = red[tx]     + red[64+tx]  + red[128+tx] + red[192+tx];
    float s2 = red[256+tx] + red[320+tx] + red[384+tx] + red[448+tx];
    atomicAdd(&stats[tx], s);
    atomicAdd(&stats[64+tx], s2);
  }
}

// fused final: coef inline; h3 = relu(aggb*scale+shift)+hbuf ;
// out = relu(h3@W1+b1)@W2+b2
__global__ __launch_bounds__(256) void k_out(
    const float* __restrict__ aggb, const float* __restrict__ stats,
    const float* __restrict__ gamma, const float* __restrict__ beta, float invN,
    const float* __restrict__ hbuf,
    const float* __restrict__ W1, const float* __restrict__ b1,
    const float* __restrict__ W2, const float* __restrict__ b2,
    float* __restrict__ out, int N)
{
  __shared__ __align__(16) float Hs[64*PAD];
  __shared__ float red[256];
  __shared__ float coefS[128];
  int tx = threadIdx.x;
  int n0 = blockIdx.x * 64;
  if (tx < 64){
    float s = stats[tx], s2 = stats[64+tx];
    float mean = s * invN;
    float var = s2 * invN - mean*mean;
    float scale = rsqrtf(var + BN_EPS) * gamma[tx];
    coefS[tx] = scale;
    coefS[64+tx] = beta[tx] - mean*scale;
  }
  __syncthreads();
  #pragma unroll
  for (int i = 0; i < 4; ++i){
    int s = tx + i*256;
    int row = s >> 4, cc = (s & 15) * 4;
    int n = n0 + row;
    float4 r = make_float4(0.f,0.f,0.f,0.f);
    if (n < N){
      float4 v = *(const float4*)&aggb[(size_t)n*HID + cc];
      r.x = fmaxf(fmaf(v.x, coefS[cc+0], coefS[64+cc+0]), 0.f);
      r.y = fmaxf(fmaf(v.y, coefS[cc+1], coefS[64+cc+1]), 0.f);
      r.z = fmaxf(fmaf(v.z, coefS[cc+2], coefS[64+cc+2]), 0.f);
      r.w = fmaxf(fmaf(v.w, coefS[cc+3], coefS[64+cc+3]), 0.f);
      float4 o = *(const float4*)&hbuf[(size_t)n*HID + cc];
      r.x += o.x; r.y += o.y; r.z += o.z; r.w += o.w;
    }
    Hs[(cc+0)*PAD + row] = r.x;
    Hs[(cc+1)*PAD + row] = r.y;
    Hs[(cc+2)*PAD + row] = r.z;
    Hs[(cc+3)*PAD + row] = r.w;
  }
  __syncthreads();
  int m = tx & 63, w = tx >> 6, j0 = w*8;
  float acc[8] = {0,0,0,0,0,0,0,0};
  #pragma unroll 8
  for (int k = 0; k < 64; ++k){
    float hv = Hs[k*PAD + m];
    #pragma unroll
    for (int j = 0; j < 8; ++j)
      acc[j] = fmaf(hv, W1[k*32 + j0 + j], acc[j]);
  }
  float part = 0.f;
  #pragma unroll
  for (int j = 0; j < 8; ++j)
    part += fmaxf(acc[j] + b1[j0+j], 0.f) * W2[j0+j];
  red[w*64 + m] = part;
  __syncthreads();
  if (tx < 64){
    int n = n0 + tx;
    if (n < N) out[n] = red[tx] + red[64+tx] + red[128+tx] + red[192+tx] + b2[0];
  }
}

extern "C" void kernel_launch(void* const* d_in, const int* in_sizes, int n_in,
                              void* d_out, int out_size, void* d_ws, size_t ws_size,
                              hipStream_t stream)
{
  const float* x         = (const float*)d_in[0];
  const int*   ei        = (const int*)d_in[1];
  const float* ew        = (const float*)d_in[2];
  const int*   positions = (const int*)d_in[3];
  const float* ftW       = (const float*)d_in[4];
  const float* ft_gamma  = (const float*)d_in[6];
  const float* ft_beta   = (const float*)d_in[7];
  const float* convW     = (const float*)d_in[8];
  const float* bn_gamma  = (const float*)d_in[10];
  const float* bn_beta   = (const float*)d_in[11];
  const float* outW1     = (const float*)d_in[12];
  const float* outb1     = (const float*)d_in[13];
  const float* outW2     = (const float*)d_in[14];
  const float* outb2     = (const float*)d_in[15];
  float* out = (float*)d_out;

  int N = in_sizes[0] / IN_DIM;
  int E = in_sizes[1] / 2;
  const int* row  = ei;
  const int* colv = ei + E;

  char* p = (char*)d_ws;
  auto alloc = [&](size_t bytes){ char* r = p; p += align256(bytes); return r; };
  float* deg      = (float*)alloc((size_t)N*4);
  float* dinv     = (float*)alloc((size_t)N*4);
  int*   cnt      = (int*)  alloc((size_t)N*4);
  int*   ptr      = (int*)  alloc((size_t)(N+1)*4);
  int*   fill     = (int*)  alloc((size_t)N*4);
  int*   bsum     = (int*)  alloc((size_t)((N+255)/256)*4);
  int2*  edges    = (int2*) alloc((size_t)E*8);
  __half* hwh     = (__half*)alloc((size_t)N*HID*2);
  float* aggb     = (float*)alloc((size_t)N*HID*4);
  float* hbuf     = (float*)alloc((size_t)N*HID*4);
  float* statsAll = (float*)alloc(512*4);   // 4 x 128 (ft, layer0..2)

  float* stats0 = statsAll;
  float* stats1 = statsAll + 128;
  float* stats2 = statsAll + 256;
  float* stats3 = statsAll + 384;

  int nb_n  = (N+255)/256;
  int nb_e  = (E+255)/256;
  int nblk  = (N+255)/256;
  int nb64  = (N+63)/64;
  int nb16  = (N+15)/16;
  float invN = 1.0f/(float)N;

  // CSR build (once; shared by all 3 layers)
  k_init  <<<nb_n,256,0,stream>>>(deg,cnt,statsAll,N);
  k_degcnt<<<nb_e,256,0,stream>>>(colv,ew,deg,cnt,E);
  k_scanA <<<nblk,256,0,stream>>>(cnt,ptr,bsum,N);
  k_scanB <<<1,256,0,stream>>>(bsum,ptr,nblk,N);
  k_scanC <<<nb_n,256,0,stream>>>(ptr,bsum,fill,deg,dinv,N);
  k_fill  <<<nb_e,256,0,stream>>>(row,colv,ew,dinv,fill,edges,E);

  // feature transform (pre-BN values -> aggb, stats fused)
  k_h0  <<<nb64,256,0,stream>>>(x,positions,ftW,aggb,stats0,N);

  // GCN layers (BN coef computed inline from stats of the previous stage)
  float* statsIn[4]  = {stats0, stats1, stats2, stats3};
  for (int i = 0; i < 3; ++i){
    const float* g = (i==0) ? ft_gamma : bn_gamma + (size_t)(i-1)*HID;
    const float* b = (i==0) ? ft_beta  : bn_beta  + (size_t)(i-1)*HID;
    k_layer<<<nb64,256,0,stream>>>(aggb,statsIn[i],g,b,invN,hbuf,
                                   convW + (size_t)i*HID*HID,hwh,N,(i>0)?1:0);
    k_agg  <<<nb16,256,0,stream>>>(hwh,ptr,edges,dinv,aggb,statsIn[i+1],N);
  }

  // final apply + output MLP
  k_out<<<nb64,256,0,stream>>>(aggb,stats3,bn_gamma+2*HID,bn_beta+2*HID,invN,
                               hbuf,outW1,outb1,outW2,outb2,out,N);
}